// Round 4
// baseline (699.868 us; speedup 1.0000x reference)
//
#include <hip/hip_runtime.h>
#include <hip/hip_bf16.h>

#define BATCH 4096
#define NGENE 3000
#define HID   6
#define GPT   30
#define T0N   500
#define T1N   50
#define KP    3008    // K padded (47 * 64)
#define MROWS 4608    // 3000 (V0 rows) + 1530 (dg mid/root) + 78 pad
#define OUTW  3857
#define BNEPS 1e-5f
#define NKT   47      // K-tiles of 64
#define BUFU  16384   // ushorts per LDS buffer: A 128x64 (8192) + B 128x64 (8192)

typedef __attribute__((ext_vector_type(8))) __bf16 bf16x8;
typedef __attribute__((ext_vector_type(4))) float f32x4;
typedef __attribute__((ext_vector_type(8))) unsigned short ushort8;

__device__ __forceinline__ unsigned short f2bf(float f) {
  unsigned int u = __builtin_bit_cast(unsigned int, f);
  u = (u + 0x7fffu + ((u >> 16) & 1u)) >> 16;
  return (unsigned short)u;
}

__device__ __forceinline__ void gload_lds16(const void* g, void* l) {
  __builtin_amdgcn_global_load_lds(
      (const __attribute__((address_space(1))) unsigned int*)g,
      (__attribute__((address_space(3))) unsigned int*)l, 16, 0, 0);
}

// ---- merged prep: cast cell -> bf16 | cast Wdg mid rows + zero tail | build bias ----
__global__ void prep(const float* __restrict__ cell, const float* __restrict__ Wdg,
                     const float* __restrict__ bdg, const float* __restrict__ W0,
                     const float* __restrict__ b0,
                     ushort8* __restrict__ cellb, ushort8* __restrict__ abuf8,
                     float* __restrict__ bias) {
  int blk = blockIdx.x;
  if (blk < 6016) {
    // cast cell fp32 -> bf16, [4096][KP], zero pad
    int idx = blk * 256 + threadIdx.x;          // < 4096*376 exactly
    int r = idx / 376, c8 = idx - r * 376;
    int c = c8 * 8;
    ushort8 o = (ushort8)0;
    if (c < NGENE) {
      const float4* p = (const float4*)(cell + (size_t)r * NGENE + c);
      float4 a = p[0], b = p[1];
      o[0] = f2bf(a.x); o[1] = f2bf(a.y); o[2] = f2bf(a.z); o[3] = f2bf(a.w);
      o[4] = f2bf(b.x); o[5] = f2bf(b.y); o[6] = f2bf(b.z); o[7] = f2bf(b.w);
    }
    cellb[idx] = o;
  } else if (blk < 8378) {
    // cast Wdg rows 15000..16529 -> abuf rows 3000..4529; zero rows 4530..4607
    int idx = (blk - 6016) * 256 + threadIdx.x;
    if (idx >= 1608 * 376) return;
    int r = idx / 376, c8 = idx - r * 376;
    int c = c8 * 8;
    ushort8 o = (ushort8)0;
    if (r < 1530 && c < NGENE) {
      const float4* p = (const float4*)(Wdg + (size_t)(15000 + r) * NGENE + c);
      float4 a = p[0], b = p[1];
      o[0] = f2bf(a.x); o[1] = f2bf(a.y); o[2] = f2bf(a.z); o[3] = f2bf(a.w);
      o[4] = f2bf(b.x); o[5] = f2bf(b.y); o[6] = f2bf(b.z); o[7] = f2bf(b.w);
    }
    abuf8[(size_t)(3000 + r) * 376 + c8] = o;
  } else {
    // bias: rows<3000 -> b0 + W0·bdg ; 3000..4529 -> bdg[15000+..] ; else 0
    int idx = (blk - 8378) * 256 + threadIdx.x;
    if (idx >= MROWS) return;
    float v = 0.f;
    if (idx < 3000) {
      int t = idx / HID;
      float s = b0[idx];
#pragma unroll
      for (int g = 0; g < GPT; ++g) s += W0[idx * GPT + g] * bdg[t * GPT + g];
      v = s;
    } else if (idx < 4530) {
      v = bdg[15000 + idx - 3000];
    }
    bias[idx] = v;
  }
}

// ---- V0[t*6+h][n] = sum_g W0[t,h,g]*Wdg[t,g,n], written bf16 into abuf ----
__global__ void v0_build(const float* __restrict__ Wdg, const float* __restrict__ W0,
                         unsigned short* __restrict__ abuf) {
  int n = blockIdx.x * 256 + threadIdx.x;   // gridDim.x=12 -> 3072
  int t = blockIdx.y;
  if (n >= KP) return;
  bool valid = n < NGENE;
  float x[GPT];
#pragma unroll
  for (int g = 0; g < GPT; ++g)
    x[g] = valid ? Wdg[((size_t)(t * GPT + g)) * NGENE + n] : 0.f;
#pragma unroll
  for (int h = 0; h < HID; ++h) {
    const float* w = W0 + (t * HID + h) * GPT;  // wave-uniform
    float s = 0.f;
#pragma unroll
    for (int g = 0; g < GPT; ++g) s += x[g] * w[g];
    abuf[((size_t)(t * HID + h)) * KP + n] = valid ? f2bf(s) : (unsigned short)0;
  }
}

// ---- GEMM: C[m][b] = A[m,:]·cell[b,:] + bias[m]; tanh for m<3000; fused L0 stats.
// 128x128 tile, BK=64, 256 thr (4 waves 2Mx2N, wave=64x64), double-buffered 64KB LDS
// -> 2 blocks/CU (8 waves/CU). Conflict-free 8-slot XOR swizzle on 128-B LDS rows
// (slot = k16 ^ (row&7); proven zero-conflict geometry from R1). Counted vmcnt(8):
// stage t+2 into the buffer freed by the post-read barrier; never drain mid-loop. ----
__global__ __launch_bounds__(256, 2) void gemm_fused(
    const unsigned short* __restrict__ A,    // [MROWS][KP] bf16
    const unsigned short* __restrict__ Bt,   // [BATCH][KP] bf16
    const float* __restrict__ bias,
    float* __restrict__ C,                   // [MROWS][BATCH] fp32
    float* __restrict__ st) {                // layer-0 stats accumulators
  extern __shared__ unsigned short smem[];   // 2 * 16384 ushorts = 65536 B
  const int tid  = threadIdx.x;
  const int wave = tid >> 6, lane = tid & 63;
  const int wm = wave >> 1, wn = wave & 1;        // 2M x 2N waves, 64x64 each
  const int quad = lane >> 4, fr = lane & 15;

  // XCD-bijective block swizzle (1152 % 8 == 0, chunk 144)
  const int bid = blockIdx.x;
  const int wg  = (bid & 7) * 144 + (bid >> 3);
  const int m0 = (wg >> 5) * 128;                 // 36 m-tiles
  const int n0 = (wg & 31) * 128;                 // 32 n-tiles

  // staging sources: LDS dest linear; global k-slot pre-swizzled (slot ^= row&7)
  // chunk c (of 1024 16B-chunks per matrix): row = c>>3, slot = c&7
  const unsigned short* srcA[4];
  const unsigned short* srcB[4];
#pragma unroll
  for (int i = 0; i < 4; ++i) {
    int c = i * 256 + tid;
    int row = c >> 3, sl = c & 7;
    srcA[i] = A  + (size_t)(m0 + row) * KP + ((sl ^ (row & 7)) << 3);
    srcB[i] = Bt + (size_t)(n0 + row) * KP + ((sl ^ (row & 7)) << 3);
  }

  f32x4 acc[4][4] = {};

  // stage K-tile kt into buffer buf (8 loads/thread: A 4 + B 4)
#define STAGE(kt, buf)                                                        \
  {                                                                           \
    unsigned short* bb = smem + (buf) * BUFU;                                 \
    const int ko = (kt) * 64;                                                 \
    _Pragma("unroll")                                                         \
    for (int i = 0; i < 4; ++i) {                                             \
      gload_lds16(srcA[i] + ko, bb + i * 2048 + wave * 512);                  \
      gload_lds16(srcB[i] + ko, bb + 8192 + i * 2048 + wave * 512);           \
    }                                                                         \
  }

  // prologue: tiles 0 and 1
  STAGE(0, 0);
  STAGE(1, 1);
  asm volatile("s_waitcnt vmcnt(8)" ::: "memory");   // own tile-0 loads retired
  __builtin_amdgcn_s_barrier();                      // => all waves' tile-0 in LDS

  // ds_read: row byte-stride 128 (full bank cycle); swizzled 16B slot = ks ^ (fr&7)
  const int ks0 = (quad ^ (fr & 7)) << 3;            // k-step 0; k-step 1 = ks0 ^ 32
  const int arow = (wm * 64 + fr) * 64;
  const int brow = 8192 + (wn * 64 + fr) * 64;

  int cur = 0;
  for (int t = 0; t < NKT; ++t) {
    const unsigned short* Ab = smem + cur * BUFU;
    bf16x8 af[4][2], bf[4][2];
#pragma unroll
    for (int tm = 0; tm < 4; ++tm) {
      af[tm][0] = *(const bf16x8*)(Ab + arow + tm * 1024 + ks0);
      af[tm][1] = *(const bf16x8*)(Ab + arow + tm * 1024 + (ks0 ^ 32));
    }
#pragma unroll
    for (int tn = 0; tn < 4; ++tn) {
      bf[tn][0] = *(const bf16x8*)(Ab + brow + tn * 1024 + ks0);
      bf[tn][1] = *(const bf16x8*)(Ab + brow + tn * 1024 + (ks0 ^ 32));
    }
    asm volatile("s_waitcnt lgkmcnt(0)" ::: "memory");  // frags in regs
    __builtin_amdgcn_s_barrier();                       // all waves done reading buf[cur]
    if (t + 2 < NKT) STAGE(t + 2, cur);                 // overwrite the freed buffer
    __builtin_amdgcn_s_setprio(1);
#pragma unroll
    for (int s = 0; s < 2; ++s)
#pragma unroll
      for (int i = 0; i < 4; ++i)
#pragma unroll
        for (int j = 0; j < 4; ++j)
          acc[i][j] = __builtin_amdgcn_mfma_f32_16x16x32_bf16(af[i][s], bf[j][s], acc[i][j], 0, 0, 0);
    __builtin_amdgcn_s_setprio(0);
    if (t + 2 < NKT)      asm volatile("s_waitcnt vmcnt(8)" ::: "memory");  // t+1 landed; t+2 in flight
    else if (t + 1 < NKT) asm volatile("s_waitcnt vmcnt(0)" ::: "memory");  // tail drain
    __builtin_amdgcn_s_barrier();                       // buf[cur^1] (= t+1) ready
    cur ^= 1;
  }
#undef STAGE

  // ---------- epilogue: bias + tanh + C write + fused layer-0 column stats ----------
  const int mbase = m0 + wm * 64 + quad * 4;
  const int nbase = n0 + wn * 64 + fr;
#pragma unroll
  for (int i = 0; i < 4; ++i) {
#pragma unroll
    for (int rr = 0; rr < 4; ++rr) {
      const int m = mbase + i * 16 + rr;
      const float bia = bias[m];
      const bool act = m < 3000;
      float s = 0.f, q = 0.f;
#pragma unroll
      for (int j = 0; j < 4; ++j) {
        float v = acc[i][j][rr] + bia;
        if (act) v = tanhf(v);
        C[(size_t)m * BATCH + nbase + j * 16] = v;
        s += v; q += v * v;
      }
      if (act) {
#pragma unroll
        for (int off = 1; off < 16; off <<= 1) {
          s += __shfl_xor(s, off);
          q += __shfl_xor(q, off);
        }
        if (fr == 0) {
          atomicAdd(&st[2 * m], s);
          atomicAdd(&st[2 * m + 1], q);
        }
      }
    }
  }
}

// ---- BN finalize ----
__global__ void bnfin(const float* __restrict__ st, const float* __restrict__ gam,
                      const float* __restrict__ bet, float* __restrict__ ss, int ncols) {
  int c = blockIdx.x * 256 + threadIdx.x;
  if (c >= ncols) return;
  float m = st[2 * c] * (1.f / BATCH);
  float v = st[2 * c + 1] * (1.f / BATCH) - m * m;
  float sc = gam[c] * rsqrtf(v + BNEPS);
  ss[2 * c] = sc;
  ss[2 * c + 1] = bet[c] - m * sc;
}

// ---- normalize zT + transpose-emit + fused aux head (66-col tiles = 11 whole terms) ----
__global__ void norm_emit_aux(const float* __restrict__ zT, const float* __restrict__ ss,
                              const float* __restrict__ aw, const float* __restrict__ ab,
                              const float* __restrict__ av, const float* __restrict__ ac,
                              float* __restrict__ out, int ncols, int outoff,
                              int auxoff, int nterm) {
  __shared__ float tile[66][65];
  int lane = threadIdx.x & 63, w = threadIdx.x >> 6;
  int c0 = blockIdx.x * 66, b0 = blockIdx.y * 64;
  for (int cc = w; cc < 66; cc += 4) {
    int c = c0 + cc;
    float n = 0.f;
    if (c < ncols)
      n = zT[(size_t)c * BATCH + b0 + lane] * ss[2 * c] + ss[2 * c + 1];
    tile[cc][lane] = n;
  }
  __syncthreads();
  // emit normalized values (transposed, coalesced over cols)
  for (int cl = lane; cl < 66; cl += 64) {
    int c = c0 + cl;
    if (c < ncols) {
#pragma unroll
      for (int i = 0; i < 16; ++i) {
        int rr = w * 16 + i;
        out[(size_t)(b0 + rr) * OUTW + outoff + c] = tile[cl][rr];
      }
    }
  }
  // aux heads for the 11 whole terms in this tile
  int t0 = c0 / 6;
  for (int tl = w; tl < 11; tl += 4) {
    int t = t0 + tl;
    if (t < nterm && c0 + tl * 6 < ncols) {
      float s = ab[t];
#pragma unroll
      for (int h = 0; h < HID; ++h) s += tile[tl * 6 + h][lane] * aw[t * HID + h];
      out[(size_t)(b0 + lane) * OUTW + auxoff + t] = tanhf(s) * av[t] + ac[t];
    }
  }
}

// ---- layer 1: z1T from normalized z0T children + raw dg mid; fused stats ----
__global__ void layer1_zT(const float* __restrict__ C, const float* __restrict__ ss0,
                          const float* __restrict__ W1, const float* __restrict__ b1,
                          float* __restrict__ z1T, float* __restrict__ st) {
  int lane = threadIdx.x & 63, tg = threadIdx.x >> 6;
  int t = blockIdx.x * 4 + tg;
  if (t >= T1N) return;
  int b = blockIdx.y * 64 + lane;
  const float* z0T = C;
  const float* dgm = C + (size_t)3000 * BATCH;
  float x[90];
#pragma unroll
  for (int j = 0; j < 60; ++j) {
    int c = t * 60 + j;
    x[j] = z0T[(size_t)c * BATCH + b] * ss0[2 * c] + ss0[2 * c + 1];
  }
#pragma unroll
  for (int g = 0; g < GPT; ++g)
    x[60 + g] = dgm[(size_t)(t * GPT + g) * BATCH + b];
#pragma unroll
  for (int h = 0; h < HID; ++h) {
    int c = t * HID + h;
    const float* w = W1 + c * 90;
    float s = b1[c];
#pragma unroll
    for (int i = 0; i < 90; ++i) s += x[i] * w[i];
    float z = tanhf(s);
    z1T[(size_t)c * BATCH + b] = z;
    float s1 = z, s2 = z * z;
#pragma unroll
    for (int off = 32; off > 0; off >>= 1) {
      s1 += __shfl_down(s1, off);
      s2 += __shfl_down(s2, off);
    }
    if (lane == 0) {
      atomicAdd(&st[2 * c], s1);
      atomicAdd(&st[2 * c + 1], s2);
    }
  }
}

// ---- root ----
__global__ void root_zT(const float* __restrict__ C, const float* __restrict__ z1T,
                        const float* __restrict__ ss1, const float* __restrict__ W2,
                        const float* __restrict__ b2, float* __restrict__ z2T,
                        float* __restrict__ st) {
  int b = blockIdx.x * 256 + threadIdx.x;
  int lane = threadIdx.x & 63;
  const float* dgr = C + (size_t)4500 * BATCH;
  float s[HID];
#pragma unroll
  for (int h = 0; h < HID; ++h) s[h] = b2[h];
  for (int c = 0; c < 300; ++c) {
    float n = z1T[(size_t)c * BATCH + b] * ss1[2 * c] + ss1[2 * c + 1];
#pragma unroll
    for (int h = 0; h < HID; ++h) s[h] += n * W2[h * 330 + c];
  }
#pragma unroll
  for (int g = 0; g < GPT; ++g) {
    float d = dgr[(size_t)g * BATCH + b];
#pragma unroll
    for (int h = 0; h < HID; ++h) s[h] += d * W2[h * 330 + 300 + g];
  }
#pragma unroll
  for (int h = 0; h < HID; ++h) {
    float z = tanhf(s[h]);
    z2T[(size_t)h * BATCH + b] = z;
    float s1 = z, s2 = z * z;
#pragma unroll
    for (int off = 32; off > 0; off >>= 1) {
      s1 += __shfl_down(s1, off);
      s2 += __shfl_down(s2, off);
    }
    if (lane == 0) {
      atomicAdd(&st[2 * h], s1);
      atomicAdd(&st[2 * h + 1], s2);
    }
  }
}

__global__ void root_emit(const float* __restrict__ z2T, const float* __restrict__ ss2,
                          const float* __restrict__ aw2, const float* __restrict__ ab2,
                          const float* __restrict__ av2, const float* __restrict__ ac2,
                          float* __restrict__ out) {
  int b = blockIdx.x * 256 + threadIdx.x;
  float s = ab2[0];
#pragma unroll
  for (int h = 0; h < HID; ++h) {
    float n = z2T[(size_t)h * BATCH + b] * ss2[2 * h] + ss2[2 * h + 1];
    out[(size_t)b * OUTW + 3851 + h] = n;
    s += n * aw2[h];
  }
  out[(size_t)b * OUTW + 550] = tanhf(s) * av2[0] + ac2[0];
}

extern "C" void kernel_launch(void* const* d_in, const int* in_sizes, int n_in,
                              void* d_out, int out_size, void* d_ws, size_t ws_size,
                              hipStream_t stream) {
  (void)in_sizes; (void)n_in; (void)out_size; (void)ws_size;
  const float* cell = (const float*)d_in[0];
  const float* Wdg  = (const float*)d_in[1];
  const float* bdg  = (const float*)d_in[2];
  const float* W0   = (const float*)d_in[3];
  const float* b0   = (const float*)d_in[4];
  const float* gam0 = (const float*)d_in[5];
  const float* bet0 = (const float*)d_in[6];
  const float* aw0  = (const float*)d_in[7];
  const float* ab0  = (const float*)d_in[8];
  const float* av0  = (const float*)d_in[9];
  const float* ac0  = (const float*)d_in[10];
  const float* W1   = (const float*)d_in[11];
  const float* b1   = (const float*)d_in[12];
  const float* gam1 = (const float*)d_in[13];
  const float* bet1 = (const float*)d_in[14];
  const float* aw1  = (const float*)d_in[15];
  const float* ab1  = (const float*)d_in[16];
  const float* av1  = (const float*)d_in[17];
  const float* ac1  = (const float*)d_in[18];
  const float* W2   = (const float*)d_in[19];
  const float* b2   = (const float*)d_in[20];
  const float* gam2 = (const float*)d_in[21];
  const float* bet2 = (const float*)d_in[22];
  const float* aw2  = (const float*)d_in[23];
  const float* ab2  = (const float*)d_in[24];
  const float* av2  = (const float*)d_in[25];
  const float* ac2  = (const float*)d_in[26];
  float* out = (float*)d_out;

  char* ws = (char*)d_ws;
  unsigned short* cellb = (unsigned short*)(ws);               // 24,641,536
  unsigned short* abuf  = (unsigned short*)(ws + 24641536);    // 27,721,728
  float*          C     = (float*)(ws + 52363264);             // 75,497,472
  float*          z1T   = (float*)(ws + 127860736);            // 4,915,200
  float*          z2T   = (float*)(ws + 132775936);            // 98,304
  float*          st    = (float*)(ws + 132874240);            // 26,448 (pad 32768)
  float*          ssb   = (float*)(ws + 132907008);            // 26,448 (pad 32768)
  float*          bias  = (float*)(ws + 132939776);            // 18,432
  float* st0 = st,  *st1 = st + 2 * 3000,  *st2 = st + 2 * 3300;
  float* ss0 = ssb, *ss1 = ssb + 2 * 3000, *ss2 = ssb + 2 * 3300;

  static int s_attr = 0;
  if (!s_attr) {
    hipFuncSetAttribute(reinterpret_cast<const void*>(gemm_fused),
                        hipFuncAttributeMaxDynamicSharedMemorySize, 65536);
    s_attr = 1;
  }

  hipMemsetAsync(st, 0, 32768, stream);   // layer0/layer1/root stat accumulators
  prep<<<8396, 256, 0, stream>>>(cell, Wdg, bdg, W0, b0,
                                 (ushort8*)cellb, (ushort8*)abuf, bias);
  v0_build<<<dim3(12, T0N), 256, 0, stream>>>(Wdg, W0, abuf);

  gemm_fused<<<1152, 256, 65536, stream>>>(abuf, cellb, bias, C, st0);

  bnfin<<<12, 256, 0, stream>>>(st0, gam0, bet0, ss0, 3000);
  norm_emit_aux<<<dim3(46, 64), 256, 0, stream>>>(C, ss0, aw0, ab0, av0, ac0,
                                                  out, 3000, 551, 0, 500);

  layer1_zT<<<dim3(13, 64), 256, 0, stream>>>(C, ss0, W1, b1, z1T, st1);
  bnfin<<<2, 256, 0, stream>>>(st1, gam1, bet1, ss1, 300);
  norm_emit_aux<<<dim3(5, 64), 256, 0, stream>>>(z1T, ss1, aw1, ab1, av1, ac1,
                                                 out, 300, 3551, 500, 50);

  root_zT<<<16, 256, 0, stream>>>(C, z1T, ss1, W2, b2, z2T, st2);
  bnfin<<<1, 256, 0, stream>>>(st2, gam2, bet2, ss2, 6);
  root_emit<<<16, 256, 0, stream>>>(z2T, ss2, aw2, ab2, av2, ac2, out);
}

// Round 5
// 626.885 us; speedup vs baseline: 1.1164x; 1.1164x over previous
//
#include <hip/hip_runtime.h>
#include <hip/hip_bf16.h>

#define BATCH 4096
#define NGENE 3000
#define HID   6
#define GPT   30
#define T0N   500
#define T1N   50
#define KP    3008    // K padded (47 * 64)
#define MROWS 4608    // 3000 (V0 rows) + 1530 (dg mid/root) + 78 pad
#define OUTW  3857
#define BNEPS 1e-5f
#define NKT   47      // K-tiles of 64
#define BUFU  16384   // ushorts per LDS buffer: A 128x64 (8192) + B 128x64 (8192)

typedef __attribute__((ext_vector_type(8))) __bf16 bf16x8;
typedef __attribute__((ext_vector_type(4))) float f32x4;
typedef __attribute__((ext_vector_type(8))) unsigned short ushort8;

__device__ __forceinline__ unsigned short f2bf(float f) {
  unsigned int u = __builtin_bit_cast(unsigned int, f);
  u = (u + 0x7fffu + ((u >> 16) & 1u)) >> 16;
  return (unsigned short)u;
}

__device__ __forceinline__ void gload_lds16(const void* g, void* l) {
  __builtin_amdgcn_global_load_lds(
      (const __attribute__((address_space(1))) unsigned int*)g,
      (__attribute__((address_space(3))) unsigned int*)l, 16, 0, 0);
}

// ---- merged prep: cast cell -> bf16 | cast Wdg mid rows + zero tail | build bias ----
__global__ void prep(const float* __restrict__ cell, const float* __restrict__ Wdg,
                     const float* __restrict__ bdg, const float* __restrict__ W0,
                     const float* __restrict__ b0,
                     ushort8* __restrict__ cellb, ushort8* __restrict__ abuf8,
                     float* __restrict__ bias) {
  int blk = blockIdx.x;
  if (blk < 6016) {
    int idx = blk * 256 + threadIdx.x;          // < 4096*376 exactly
    int r = idx / 376, c8 = idx - r * 376;
    int c = c8 * 8;
    ushort8 o = (ushort8)0;
    if (c < NGENE) {
      const float4* p = (const float4*)(cell + (size_t)r * NGENE + c);
      float4 a = p[0], b = p[1];
      o[0] = f2bf(a.x); o[1] = f2bf(a.y); o[2] = f2bf(a.z); o[3] = f2bf(a.w);
      o[4] = f2bf(b.x); o[5] = f2bf(b.y); o[6] = f2bf(b.z); o[7] = f2bf(b.w);
    }
    cellb[idx] = o;
  } else if (blk < 8378) {
    int idx = (blk - 6016) * 256 + threadIdx.x;
    if (idx >= 1608 * 376) return;
    int r = idx / 376, c8 = idx - r * 376;
    int c = c8 * 8;
    ushort8 o = (ushort8)0;
    if (r < 1530 && c < NGENE) {
      const float4* p = (const float4*)(Wdg + (size_t)(15000 + r) * NGENE + c);
      float4 a = p[0], b = p[1];
      o[0] = f2bf(a.x); o[1] = f2bf(a.y); o[2] = f2bf(a.z); o[3] = f2bf(a.w);
      o[4] = f2bf(b.x); o[5] = f2bf(b.y); o[6] = f2bf(b.z); o[7] = f2bf(b.w);
    }
    abuf8[(size_t)(3000 + r) * 376 + c8] = o;
  } else {
    int idx = (blk - 8378) * 256 + threadIdx.x;
    if (idx >= MROWS) return;
    float v = 0.f;
    if (idx < 3000) {
      int t = idx / HID;
      float s = b0[idx];
#pragma unroll
      for (int g = 0; g < GPT; ++g) s += W0[idx * GPT + g] * bdg[t * GPT + g];
      v = s;
    } else if (idx < 4530) {
      v = bdg[15000 + idx - 3000];
    }
    bias[idx] = v;
  }
}

// ---- V0[t*6+h][n] = sum_g W0[t,h,g]*Wdg[t,g,n], written bf16 into abuf ----
__global__ void v0_build(const float* __restrict__ Wdg, const float* __restrict__ W0,
                         unsigned short* __restrict__ abuf) {
  int n = blockIdx.x * 256 + threadIdx.x;   // gridDim.x=12 -> 3072
  int t = blockIdx.y;
  if (n >= KP) return;
  bool valid = n < NGENE;
  float x[GPT];
#pragma unroll
  for (int g = 0; g < GPT; ++g)
    x[g] = valid ? Wdg[((size_t)(t * GPT + g)) * NGENE + n] : 0.f;
#pragma unroll
  for (int h = 0; h < HID; ++h) {
    const float* w = W0 + (t * HID + h) * GPT;  // wave-uniform
    float s = 0.f;
#pragma unroll
    for (int g = 0; g < GPT; ++g) s += x[g] * w[g];
    abuf[((size_t)(t * HID + h)) * KP + n] = valid ? f2bf(s) : (unsigned short)0;
  }
}

// ---- GEMM: C[m][b] = A[m,:]·cell[b,:] + bias[m]; tanh for m<3000; fused L0 stats.
// 128x128 tile, BK=64, 4 waves (64x64 each), double-buffered 64KB LDS, 2 blocks/CU.
// Plain n-fastest grid (no XCD swizzle): all XCDs sweep the same m-band together,
// so the B-stream is shared via L2/LLC (R0 measured 132 MB fetch vs 404 swizzled).
// Conflict-free 8-slot XOR swizzle; counted vmcnt(8); k0-MFMA overlapped with
// k1 ds_read latency. ----
__global__ __launch_bounds__(256, 2) void gemm_fused(
    const unsigned short* __restrict__ A,    // [MROWS][KP] bf16
    const unsigned short* __restrict__ Bt,   // [BATCH][KP] bf16
    const float* __restrict__ bias,
    float* __restrict__ C,                   // [MROWS][BATCH] fp32
    float* __restrict__ st) {                // layer-0 stats accumulators
  extern __shared__ unsigned short smem[];   // 2 * 16384 ushorts = 65536 B
  const int tid  = threadIdx.x;
  const int wave = tid >> 6, lane = tid & 63;
  const int wm = wave >> 1, wn = wave & 1;        // 2M x 2N waves, 64x64 each
  const int quad = lane >> 4, fr = lane & 15;

  const int m0 = blockIdx.y * 128;                // 36 m-tiles
  const int n0 = blockIdx.x * 128;                // 32 n-tiles

  // staging sources: LDS dest linear; global k-slot pre-swizzled (slot ^= row&7)
  const unsigned short* srcA[4];
  const unsigned short* srcB[4];
#pragma unroll
  for (int i = 0; i < 4; ++i) {
    int c = i * 256 + tid;
    int row = c >> 3, sl = c & 7;
    srcA[i] = A  + (size_t)(m0 + row) * KP + ((sl ^ (row & 7)) << 3);
    srcB[i] = Bt + (size_t)(n0 + row) * KP + ((sl ^ (row & 7)) << 3);
  }

  f32x4 acc[4][4] = {};

#define STAGE(kt, buf)                                                        \
  {                                                                           \
    unsigned short* bb = smem + (buf) * BUFU;                                 \
    const int ko = (kt) * 64;                                                 \
    _Pragma("unroll")                                                         \
    for (int i = 0; i < 4; ++i) {                                             \
      gload_lds16(srcA[i] + ko, bb + i * 2048 + wave * 512);                  \
      gload_lds16(srcB[i] + ko, bb + 8192 + i * 2048 + wave * 512);           \
    }                                                                         \
  }

  STAGE(0, 0);
  STAGE(1, 1);
  asm volatile("s_waitcnt vmcnt(8)" ::: "memory");   // own tile-0 loads retired
  __builtin_amdgcn_s_barrier();                      // => all waves' tile-0 in LDS

  const int ks0 = (quad ^ (fr & 7)) << 3;            // k-step 0; k-step 1 = ks0 ^ 32
  const int arow = (wm * 64 + fr) * 64;
  const int brow = 8192 + (wn * 64 + fr) * 64;

  int cur = 0;
  for (int t = 0; t < NKT; ++t) {
    const unsigned short* Ab = smem + cur * BUFU;
    bf16x8 af[4][2], bf[4][2];
#pragma unroll
    for (int tm = 0; tm < 4; ++tm) af[tm][0] = *(const bf16x8*)(Ab + arow + tm * 1024 + ks0);
#pragma unroll
    for (int tn = 0; tn < 4; ++tn) bf[tn][0] = *(const bf16x8*)(Ab + brow + tn * 1024 + ks0);
#pragma unroll
    for (int tm = 0; tm < 4; ++tm) af[tm][1] = *(const bf16x8*)(Ab + arow + tm * 1024 + (ks0 ^ 32));
#pragma unroll
    for (int tn = 0; tn < 4; ++tn) bf[tn][1] = *(const bf16x8*)(Ab + brow + tn * 1024 + (ks0 ^ 32));
    // k0 cluster runs under k1 ds_read latency (compiler tracks frag deps)
    __builtin_amdgcn_s_setprio(1);
#pragma unroll
    for (int i = 0; i < 4; ++i)
#pragma unroll
      for (int j = 0; j < 4; ++j)
        acc[i][j] = __builtin_amdgcn_mfma_f32_16x16x32_bf16(af[i][0], bf[j][0], acc[i][j], 0, 0, 0);
    __builtin_amdgcn_s_setprio(0);
    asm volatile("s_waitcnt lgkmcnt(0)" ::: "memory");  // ALL reads of buf[cur] done
    __builtin_amdgcn_s_barrier();                       // all waves done reading
    if (t + 2 < NKT) STAGE(t + 2, cur);                 // overwrite the freed buffer
    __builtin_amdgcn_s_setprio(1);
#pragma unroll
    for (int i = 0; i < 4; ++i)
#pragma unroll
      for (int j = 0; j < 4; ++j)
        acc[i][j] = __builtin_amdgcn_mfma_f32_16x16x32_bf16(af[i][1], bf[j][1], acc[i][j], 0, 0, 0);
    __builtin_amdgcn_s_setprio(0);
    if (t + 2 < NKT)      asm volatile("s_waitcnt vmcnt(8)" ::: "memory");  // t+1 landed; t+2 in flight
    else if (t + 1 < NKT) asm volatile("s_waitcnt vmcnt(0)" ::: "memory");  // tail drain
    __builtin_amdgcn_s_barrier();                       // buf[cur^1] (= t+1) ready
    cur ^= 1;
  }
#undef STAGE

  // epilogue: bias + tanh + C write + fused layer-0 column stats
  const int mbase = m0 + wm * 64 + quad * 4;
  const int nbase = n0 + wn * 64 + fr;
#pragma unroll
  for (int i = 0; i < 4; ++i) {
#pragma unroll
    for (int rr = 0; rr < 4; ++rr) {
      const int m = mbase + i * 16 + rr;
      const float bia = bias[m];
      const bool act = m < 3000;
      float s = 0.f, q = 0.f;
#pragma unroll
      for (int j = 0; j < 4; ++j) {
        float v = acc[i][j][rr] + bia;
        if (act) v = tanhf(v);
        C[(size_t)m * BATCH + nbase + j * 16] = v;
        s += v; q += v * v;
      }
      if (act) {
#pragma unroll
        for (int off = 1; off < 16; off <<= 1) {
          s += __shfl_xor(s, off);
          q += __shfl_xor(q, off);
        }
        if (fr == 0) {
          atomicAdd(&st[2 * m], s);
          atomicAdd(&st[2 * m + 1], q);
        }
      }
    }
  }
}

// ---- fused stage 1: bnfin0 (per-block) + norm-emit z0 + aux0 + layer1 + stats1.
// grid (50, 64): block = (term t, 64-batch tile). Reads C's z0 columns ONCE. ----
__global__ void fuse_l1(const float* __restrict__ C, const float* __restrict__ st0,
                        const float* __restrict__ gam0, const float* __restrict__ bet0,
                        const float* __restrict__ aw0, const float* __restrict__ ab0,
                        const float* __restrict__ av0, const float* __restrict__ ac0,
                        const float* __restrict__ W1, const float* __restrict__ b1,
                        float* __restrict__ out, float* __restrict__ z1T,
                        float* __restrict__ st1) {
  __shared__ float tile[60][65];   // normalized z0 cols of this term
  __shared__ float dgt[30][65];    // raw dg mid rows of this term
  __shared__ float ssl[120];
  const int t = blockIdx.x, b0 = blockIdx.y * 64;
  const int lane = threadIdx.x & 63, w = threadIdx.x >> 6;
  if (threadIdx.x < 60) {
    int c = t * 60 + threadIdx.x;
    float m = st0[2 * c] * (1.f / BATCH);
    float v = st0[2 * c + 1] * (1.f / BATCH) - m * m;
    float sc = gam0[c] * rsqrtf(v + BNEPS);
    ssl[2 * threadIdx.x] = sc;
    ssl[2 * threadIdx.x + 1] = bet0[c] - m * sc;
  }
  __syncthreads();
  for (int cc = w; cc < 60; cc += 4)
    tile[cc][lane] = C[(size_t)(t * 60 + cc) * BATCH + b0 + lane] * ssl[2 * cc] + ssl[2 * cc + 1];
  for (int g = w; g < GPT; g += 4)
    dgt[g][lane] = C[(size_t)(3000 + t * GPT + g) * BATCH + b0 + lane];
  __syncthreads();
  // emit normalized z0 (transposed, out cols 551 + t*60 + c)
  if (lane < 60) {
#pragma unroll
    for (int i = 0; i < 16; ++i)
      out[(size_t)(b0 + w * 16 + i) * OUTW + 551 + t * 60 + lane] = tile[lane][w * 16 + i];
  }
  // aux heads for leaf terms 10t..10t+9
  for (int tl = w; tl < 10; tl += 4) {
    int tt = t * 10 + tl;
    float s = ab0[tt];
#pragma unroll
    for (int h = 0; h < HID; ++h) s += tile[tl * 6 + h][lane] * aw0[tt * HID + h];
    out[(size_t)(b0 + lane) * OUTW + tt] = tanhf(s) * av0[tt] + ac0[tt];
  }
  // layer1 for term t: waves 0..2 compute 2 h each
  if (w < 3) {
#pragma unroll
    for (int hh = 0; hh < 2; ++hh) {
      int h = w * 2 + hh, c = t * HID + h;
      const float* wr = W1 + c * 90;
      float s = b1[c];
#pragma unroll
      for (int j = 0; j < 60; ++j) s += tile[j][lane] * wr[j];
#pragma unroll
      for (int g = 0; g < GPT; ++g) s += dgt[g][lane] * wr[60 + g];
      float z = tanhf(s);
      z1T[(size_t)c * BATCH + b0 + lane] = z;
      float s1 = z, s2 = z * z;
#pragma unroll
      for (int off = 32; off > 0; off >>= 1) {
        s1 += __shfl_down(s1, off);
        s2 += __shfl_down(s2, off);
      }
      if (lane == 0) {
        atomicAdd(&st1[2 * c], s1);
        atomicAdd(&st1[2 * c + 1], s2);
      }
    }
  }
}

// ---- fused stage 2: blocks 0..319 = bnfin1 + norm-emit z1 + aux1; 320..335 = root.
__global__ void fuse_l2(const float* __restrict__ C, const float* __restrict__ z1T,
                        const float* __restrict__ st1,
                        const float* __restrict__ gam1, const float* __restrict__ bet1,
                        const float* __restrict__ aw1, const float* __restrict__ ab1,
                        const float* __restrict__ av1, const float* __restrict__ ac1,
                        const float* __restrict__ W2, const float* __restrict__ b2,
                        float* __restrict__ out, float* __restrict__ z2T,
                        float* __restrict__ st2) {
  const int blk = blockIdx.x;
  if (blk < 320) {
    __shared__ float tile[60][65];
    __shared__ float ssl[120];
    const int q = blk >> 6, b0 = (blk & 63) * 64;   // q: 5 col-tiles of 60
    const int lane = threadIdx.x & 63, w = threadIdx.x >> 6;
    if (threadIdx.x < 60) {
      int c = q * 60 + threadIdx.x;
      float m = st1[2 * c] * (1.f / BATCH);
      float v = st1[2 * c + 1] * (1.f / BATCH) - m * m;
      float sc = gam1[c] * rsqrtf(v + BNEPS);
      ssl[2 * threadIdx.x] = sc;
      ssl[2 * threadIdx.x + 1] = bet1[c] - m * sc;
    }
    __syncthreads();
    for (int cc = w; cc < 60; cc += 4)
      tile[cc][lane] = z1T[(size_t)(q * 60 + cc) * BATCH + b0 + lane] * ssl[2 * cc] + ssl[2 * cc + 1];
    __syncthreads();
    if (lane < 60) {
#pragma unroll
      for (int i = 0; i < 16; ++i)
        out[(size_t)(b0 + w * 16 + i) * OUTW + 3551 + q * 60 + lane] = tile[lane][w * 16 + i];
    }
    for (int tl = w; tl < 10; tl += 4) {
      int tt = q * 10 + tl;
      float s = ab1[tt];
#pragma unroll
      for (int h = 0; h < HID; ++h) s += tile[tl * 6 + h][lane] * aw1[tt * HID + h];
      out[(size_t)(b0 + lane) * OUTW + 500 + tt] = tanhf(s) * av1[tt] + ac1[tt];
    }
  } else {
    // root: z2 = tanh(W2 · [normalized z1 ; dg root] + b2), stats2
    __shared__ float ssl[600];
    const int b = (blk - 320) * 256 + threadIdx.x;
    const int lane = threadIdx.x & 63;
    for (int c = threadIdx.x; c < 300; c += 256) {
      float m = st1[2 * c] * (1.f / BATCH);
      float v = st1[2 * c + 1] * (1.f / BATCH) - m * m;
      float sc = gam1[c] * rsqrtf(v + BNEPS);
      ssl[2 * c] = sc;
      ssl[2 * c + 1] = bet1[c] - m * sc;
    }
    __syncthreads();
    const float* dgr = C + (size_t)4500 * BATCH;
    float s[HID];
#pragma unroll
    for (int h = 0; h < HID; ++h) s[h] = b2[h];
    for (int c = 0; c < 300; ++c) {
      float n = z1T[(size_t)c * BATCH + b] * ssl[2 * c] + ssl[2 * c + 1];
#pragma unroll
      for (int h = 0; h < HID; ++h) s[h] += n * W2[h * 330 + c];
    }
#pragma unroll
    for (int g = 0; g < GPT; ++g) {
      float d = dgr[(size_t)g * BATCH + b];
#pragma unroll
      for (int h = 0; h < HID; ++h) s[h] += d * W2[h * 330 + 300 + g];
    }
#pragma unroll
    for (int h = 0; h < HID; ++h) {
      float z = tanhf(s[h]);
      z2T[(size_t)h * BATCH + b] = z;
      float s1 = z, s2 = z * z;
#pragma unroll
      for (int off = 32; off > 0; off >>= 1) {
        s1 += __shfl_down(s1, off);
        s2 += __shfl_down(s2, off);
      }
      if (lane == 0) {
        atomicAdd(&st2[2 * h], s1);
        atomicAdd(&st2[2 * h + 1], s2);
      }
    }
  }
}

// ---- root emit with inline bnfin2 ----
__global__ void root_emit(const float* __restrict__ z2T, const float* __restrict__ st2,
                          const float* __restrict__ gam2, const float* __restrict__ bet2,
                          const float* __restrict__ aw2, const float* __restrict__ ab2,
                          const float* __restrict__ av2, const float* __restrict__ ac2,
                          float* __restrict__ out) {
  int b = blockIdx.x * 256 + threadIdx.x;
  float s = ab2[0];
#pragma unroll
  for (int h = 0; h < HID; ++h) {
    float m = st2[2 * h] * (1.f / BATCH);
    float v = st2[2 * h + 1] * (1.f / BATCH) - m * m;
    float sc = gam2[h] * rsqrtf(v + BNEPS);
    float sh = bet2[h] - m * sc;
    float n = z2T[(size_t)h * BATCH + b] * sc + sh;
    out[(size_t)b * OUTW + 3851 + h] = n;
    s += n * aw2[h];
  }
  out[(size_t)b * OUTW + 550] = tanhf(s) * av2[0] + ac2[0];
}

extern "C" void kernel_launch(void* const* d_in, const int* in_sizes, int n_in,
                              void* d_out, int out_size, void* d_ws, size_t ws_size,
                              hipStream_t stream) {
  (void)in_sizes; (void)n_in; (void)out_size; (void)ws_size;
  const float* cell = (const float*)d_in[0];
  const float* Wdg  = (const float*)d_in[1];
  const float* bdg  = (const float*)d_in[2];
  const float* W0   = (const float*)d_in[3];
  const float* b0   = (const float*)d_in[4];
  const float* gam0 = (const float*)d_in[5];
  const float* bet0 = (const float*)d_in[6];
  const float* aw0  = (const float*)d_in[7];
  const float* ab0  = (const float*)d_in[8];
  const float* av0  = (const float*)d_in[9];
  const float* ac0  = (const float*)d_in[10];
  const float* W1   = (const float*)d_in[11];
  const float* b1   = (const float*)d_in[12];
  const float* gam1 = (const float*)d_in[13];
  const float* bet1 = (const float*)d_in[14];
  const float* aw1  = (const float*)d_in[15];
  const float* ab1  = (const float*)d_in[16];
  const float* av1  = (const float*)d_in[17];
  const float* ac1  = (const float*)d_in[18];
  const float* W2   = (const float*)d_in[19];
  const float* b2   = (const float*)d_in[20];
  const float* gam2 = (const float*)d_in[21];
  const float* bet2 = (const float*)d_in[22];
  const float* aw2  = (const float*)d_in[23];
  const float* ab2  = (const float*)d_in[24];
  const float* av2  = (const float*)d_in[25];
  const float* ac2  = (const float*)d_in[26];
  float* out = (float*)d_out;

  char* ws = (char*)d_ws;
  unsigned short* cellb = (unsigned short*)(ws);               // 24,641,536
  unsigned short* abuf  = (unsigned short*)(ws + 24641536);    // 27,721,728
  float*          C     = (float*)(ws + 52363264);             // 75,497,472
  float*          z1T   = (float*)(ws + 127860736);            // 4,915,200
  float*          z2T   = (float*)(ws + 132775936);            // 98,304
  float*          st    = (float*)(ws + 132874240);            // 26,448 (pad 32768)
  float*          bias  = (float*)(ws + 132939776);            // 18,432
  float* st0 = st, *st1 = st + 2 * 3000, *st2 = st + 2 * 3300;

  static int s_attr = 0;
  if (!s_attr) {
    hipFuncSetAttribute(reinterpret_cast<const void*>(gemm_fused),
                        hipFuncAttributeMaxDynamicSharedMemorySize, 65536);
    s_attr = 1;
  }

  hipMemsetAsync(st, 0, 32768, stream);   // layer0/layer1/root stat accumulators
  prep<<<8396, 256, 0, stream>>>(cell, Wdg, bdg, W0, b0,
                                 (ushort8*)cellb, (ushort8*)abuf, bias);
  v0_build<<<dim3(12, T0N), 256, 0, stream>>>(Wdg, W0, abuf);

  gemm_fused<<<dim3(32, 36), 256, 65536, stream>>>(abuf, cellb, bias, C, st0);

  fuse_l1<<<dim3(50, 64), 256, 0, stream>>>(C, st0, gam0, bet0, aw0, ab0, av0, ac0,
                                            W1, b1, out, z1T, st1);
  fuse_l2<<<336, 256, 0, stream>>>(C, z1T, st1, gam1, bet1, aw1, ab1, av1, ac1,
                                   W2, b2, out, z2T, st2);
  root_emit<<<16, 256, 0, stream>>>(z2T, st2, gam2, bet2, aw2, ab2, av2, ac2, out);
}